// Round 14
// baseline (600.017 us; speedup 1.0000x reference)
//
#include <hip/hip_runtime.h>

// Sinkhorn divergence, 512 independent 256-point problems, 24 annealing steps.
// Round 16: R13 (546us best: column-pair packed v2f math, pure C, 1 barrier/
// step) x R10's half-column occupancy doubling. NT=1024, 2 blocks/CU =
// 8 waves/SIMD (R13 ran 4: VALUBusy 86% @ 36% occupancy = trans-latency
// visible, issue port unsaturated -> more waves should close it).
//   pair = tid>>9 (0: A={xy->f, yy->py} over y-side; 1: B={yx->g, xx->px}
//   over x-side); half = lane>>5 (0: groups 0-63; 1: groups 64-127);
//   row = ((wave&7)<<5)|(lane&31). Half-merge is register-only and exact
//   (2 shfl_xor + integer-ldexp, canonical lo/hi order; R10-verified).
// VGPR cap 64 (launch_bounds(1024,8)); R13 measured 52. WRITE_SIZE is the
// spill detector — a jump means v2f demotion returned (R3/R4), revert.
// LDS (12.8 KB): yaH[2][128], xaH[2][128] H quads; yaW/xaW[128] coord
// quads {z_2k, z_2k+1, t_2k, t_2k+1}; packed multiplicands loop-invariant.
// Math: online logsumexp, integer-quantized running max (ceilf), ldexp
// rescale — exact; packed sum tree reassociates (threshold 5.48).

constexpr int   N       = 256;   // points per cloud
constexpr int   NPROB   = 512;   // B*S*NR
constexpr int   NRDIM   = 64;
constexpr float DT_F    = 0.001f;
constexpr float EPS_MIN = 1e-4f; // BLUR^P
constexpr int   NSTEPS  = 24;
constexpr float LOG2E   = 1.4426950408889634f;
constexpr float LN2     = 0.6931471805599453f;
constexpr int   NT      = 1024;  // threads per block (16 waves)
constexpr int   NG      = N / 2; // 128 column-pair groups

typedef float v2f __attribute__((ext_vector_type(2)));

extern "C" __global__ void __launch_bounds__(NT, 8)
sinkhorn_div_kernel(const float* __restrict__ syn,
                    const float* __restrict__ obs,
                    float* __restrict__ divs)
{
    const int p    = blockIdx.x;         // ((b*S + s)*NR + r)
    const int r    = p & (NRDIM - 1);
    const int bs   = p >> 6;
    const int tid  = threadIdx.x;
    const int lane = tid & 63;
    const int wave = tid >> 6;           // 0..15
    const int pair = tid >> 9;           // 0: A over y-side ; 1: B over x-side
    const int half = lane >> 5;          // 0: groups 0-63 ; 1: groups 64-127
    const int row  = ((wave & 7) << 5) | (lane & 31);   // 0..255

    __shared__ float4 yaH[2][NG];        // y-side H per buf (4 KB)
    __shared__ float4 xaH[2][NG];        // x-side H per buf (4 KB)
    __shared__ float4 yaW[NG];           // y-side coords (2 KB, static)
    __shared__ float4 xaW[NG];           // x-side coords (2 KB, static)
    __shared__ float  redA[64];

    float* yaHF = (float*)yaH;           // word views: buf*512 + wslot
    float* xaHF = (float*)xaH;
    float* yaWF = (float*)yaW;
    float* xaWF = (float*)xaW;

    const size_t base = (size_t)bs * N * NRDIM + r;
    const float xi = obs[base + (size_t)row * NRDIM];   // x cloud = obs
    const float yi = syn[base + (size_t)row * NRDIM];   // y cloud = syn
    const float ti = (float)row * DT_F;

    // word slot of column `row`: group g=row>>1, H1/z at g*4+(row&1), H2/t at +2
    const int wslot = ((row >> 1) << 2) | (row & 1);    // 0..509

    // ---- one-time init: static column coords (half 0 only) ----
    if (half == 0) {
        if (pair == 0) {
            yaWF[wslot]     = yi;
            yaWF[wslot + 2] = ti;
        } else {
            xaWF[wslot]     = xi;
            xaWF[wslot + 2] = ti;
        }
    }

    // ---- block reductions: diameter (max/min) + all-zero mask sums ----
    // (rows duplicated across pairs/halves: fine for max/min & zero-tests)
    float hi = fmaxf(xi, yi), lo = fminf(xi, yi);
    float ax = fabsf(xi),     ay = fabsf(yi);
    #pragma unroll
    for (int off = 32; off > 0; off >>= 1) {
        hi  = fmaxf(hi, __shfl_down(hi, off, 64));
        lo  = fminf(lo, __shfl_down(lo, off, 64));
        ax += __shfl_down(ax, off, 64);
        ay += __shfl_down(ay, off, 64);
    }
    if ((tid & 63) == 0) {
        redA[wave * 4 + 0] = hi;  redA[wave * 4 + 1] = lo;
        redA[wave * 4 + 2] = ax;  redA[wave * 4 + 3] = ay;
    }
    __syncthreads();                     // also covers coord init writes
    float vmax = -3.4e38f, vmin = 3.4e38f, sax = 0.0f, say = 0.0f;
    #pragma unroll
    for (int w = 0; w < 16; ++w) {
        vmax = fmaxf(vmax, redA[w * 4 + 0]);
        vmin = fminf(vmin, redA[w * 4 + 1]);
        sax += redA[w * 4 + 2];
        say += redA[w * 4 + 3];
    }

    const float tspread  = 255.0f * DT_F;
    const float diameter = fmaxf(tspread, vmax - vmin);
    float eps_raw = diameter * diameter;              // eps0 = diameter^2

    const float selfx = 0.5f * (ti * ti + xi * xi);
    const float selfy = 0.5f * (ti * ti + yi * yi);
    const float la2   = -8.0f;                        // log2(1/256)

    // pair A: pot1=f (selfx, xi) reads y-side; pot2=py (selfy, yi)
    // pair B: pot1=g (selfy, yi) reads x-side; pot2=px (selfx, xi)
    const float self1 = (pair == 0) ? selfx : selfy;
    const float self2 = (pair == 0) ? selfy : selfx;
    const float cf1   = (pair == 0) ? xi : yi;
    const float cf2   = (pair == 0) ? yi : xi;

    float pot1 = 0.0f, pot2 = 0.0f;

    const int ghalf = half << 6;         // my group range start (0 or 64)

#define EXP2(x) __builtin_amdgcn_exp2f(x)

// One 2-column group: Q = H quad, W = coord quad -> packed args AB (stream1),
// AC (stream2). Multiplicand pairs are loop-invariant; pure-C v2f fma.
#define GRP(Q, W, AB, AC) do { \
        const v2f hb_ = {Q.x, Q.y}; const v2f hc_ = {Q.z, Q.w}; \
        const v2f zz_ = {W.x, W.y}; const v2f tt_ = {W.z, W.w}; \
        AB = __builtin_elementwise_fma(zz_, c1v, \
                 __builtin_elementwise_fma(tt_, tii2, hb_)); \
        AC = __builtin_elementwise_fma(zz_, c2v, \
                 __builtin_elementwise_fma(tt_, tii2, hc_)); \
    } while (0)

    for (int step = 0; step < NSTEPS; ++step) {
        const float eps = fmaxf(eps_raw, EPS_MIN);
        const float inv = LOG2E / eps;
        const int   buf = step & 1;
        const int   bo  = buf * (NG * 4);        // word offset of H buffer

        // ---- prologue: half 0 cross-feeds potentials as next H columns ----
        if (half == 0) {
            const float h1 = fmaf(pot1 - self1, inv, la2);
            const float h2 = fmaf(pot2 - self2, inv, la2);
            if (pair == 0) {      // f -> Hyx (x-side H1) ; py -> Hyy (y-side H2)
                xaHF[bo + wslot]     = h1;
                yaHF[bo + wslot + 2] = h2;
            } else {              // g -> Hxy (y-side H1) ; px -> Hxx (x-side H2)
                yaHF[bo + wslot]     = h1;
                xaHF[bo + wslot + 2] = h2;
            }
        }
        __syncthreads();          // the ONLY barrier this step

        const float tii = ti * inv;
        const v2f tii2 = {tii, tii};
        const v2f c1v  = {cf1 * inv, cf1 * inv};
        const v2f c2v  = {cf2 * inv, cf2 * inv};
        const float4* __restrict__ Hq = (pair == 0) ? &yaH[buf][0] : &xaH[buf][0];
        const float4* __restrict__ Wq = (pair == 0) ? &yaW[0]      : &xaW[0];

        float m0 = -1e9f, m1 = -1e9f, s0 = 0.0f, s1 = 0.0f;
        #pragma unroll 2
        for (int cc = 0; cc < 64; cc += 4) {     // 4 groups = 8 columns
            const int k = ghalf + cc;
            const float4 Q0 = Hq[k + 0];
            const float4 Q1 = Hq[k + 1];
            const float4 Q2 = Hq[k + 2];
            const float4 Q3 = Hq[k + 3];
            const float4 W0 = Wq[k + 0];
            const float4 W1 = Wq[k + 1];
            const float4 W2 = Wq[k + 2];
            const float4 W3 = Wq[k + 3];
            v2f ab0, ab1, ab2, ab3, ac0, ac1, ac2, ac3;
            GRP(Q0, W0, ab0, ac0);
            GRP(Q1, W1, ab1, ac1);
            GRP(Q2, W2, ab2, ac2);
            GRP(Q3, W3, ab3, ac3);
            // scalar max trees on pair halves; m0/m1 integer-valued
            // (or -1e9) -> folding before ceil stays exact
            const float bt0 = fmaxf(fmaxf(ab0.x, ab0.y), ab1.x);
            const float bt1 = fmaxf(fmaxf(ab1.y, ab2.x), ab2.y);
            const float bt2 = fmaxf(fmaxf(ab3.x, ab3.y), m0);
            const float M0  = ceilf(fmaxf(fmaxf(bt0, bt1), bt2));
            const float ct0 = fmaxf(fmaxf(ac0.x, ac0.y), ac1.x);
            const float ct1 = fmaxf(fmaxf(ac1.y, ac2.x), ac2.y);
            const float ct2 = fmaxf(fmaxf(ac3.x, ac3.y), m1);
            const float M1  = ceilf(fmaxf(fmaxf(ct0, ct1), ct2));
            const v2f M0v = {M0, M0};
            const v2f M1v = {M1, M1};
            const v2f ub0 = ab0 - M0v, ub1 = ab1 - M0v;
            const v2f ub2 = ab2 - M0v, ub3 = ab3 - M0v;
            const v2f uc0 = ac0 - M1v, uc1 = ac1 - M1v;
            const v2f uc2 = ac2 - M1v, uc3 = ac3 - M1v;
            v2f eb0, eb1, eb2, eb3, ec0, ec1, ec2, ec3;
            eb0.x = EXP2(ub0.x); eb0.y = EXP2(ub0.y);
            eb1.x = EXP2(ub1.x); eb1.y = EXP2(ub1.y);
            eb2.x = EXP2(ub2.x); eb2.y = EXP2(ub2.y);
            eb3.x = EXP2(ub3.x); eb3.y = EXP2(ub3.y);
            ec0.x = EXP2(uc0.x); ec0.y = EXP2(uc0.y);
            ec1.x = EXP2(uc1.x); ec1.y = EXP2(uc1.y);
            ec2.x = EXP2(uc2.x); ec2.y = EXP2(uc2.y);
            ec3.x = EXP2(uc3.x); ec3.y = EXP2(uc3.y);
            const v2f pb0 = eb0 + eb1, pb1 = eb2 + eb3;
            const v2f qb  = pb0 + pb1;
            const v2f pc0 = ec0 + ec1, pc1 = ec2 + ec3;
            const v2f qc  = pc0 + pc1;
            s0 = ldexpf(s0, (int)(m0 - M0)) + (qb.x + qb.y);  m0 = M0;
            s1 = ldexpf(s1, (int)(m1 - M1)) + (qc.x + qc.y);  m1 = M1;
        }

        // ---- register-only half-merge (canonical lo/hi order: both halves
        //      compute bit-identical results; m's integer-valued -> exact) --
        {
            const float mo = __shfl_xor(m0, 32, 64);
            const float so = __shfl_xor(s0, 32, 64);
            const float ml = (half == 0) ? m0 : mo;
            const float sl = (half == 0) ? s0 : so;
            const float mh = (half == 0) ? mo : m0;
            const float sh = (half == 0) ? so : s0;
            m0 = fmaxf(ml, mh);
            s0 = ldexpf(sl, (int)(ml - m0)) + ldexpf(sh, (int)(mh - m0));
        }
        {
            const float mo = __shfl_xor(m1, 32, 64);
            const float so = __shfl_xor(s1, 32, 64);
            const float ml = (half == 0) ? m1 : mo;
            const float sl = (half == 0) ? s1 : so;
            const float mh = (half == 0) ? mo : m1;
            const float sh = (half == 0) ? so : s1;
            m1 = fmaxf(ml, mh);
            s1 = ldexpf(sl, (int)(ml - m1)) + ldexpf(sh, (int)(mh - m1));
        }

        // ---- epilogue: thread-local softmin finish (2 logs) ----
        const float el2 = eps * LN2;
        pot1 = self1 - el2 * (m0 + __builtin_amdgcn_logf(s0));                  // f / g
        pot2 = 0.5f * (pot2 + (self2 - el2 * (m1 + __builtin_amdgcn_logf(s1)))); // py / px

        eps_raw *= 0.25f;
        // next prologue writes buf^1; step t's reads of buf are separated
        // from step t+2's writes of buf by step t+1's barrier.
    }
#undef GRP
#undef EXP2

    // ---- divergence: half 0 holds (f - py) [pair A] / (g - px) [pair B] ----
    float contrib = (half == 0) ? (pot1 - pot2) : 0.0f;
    #pragma unroll
    for (int off = 32; off > 0; off >>= 1)
        contrib += __shfl_down(contrib, off, 64);
    __syncthreads();                      // redA reuse
    if ((tid & 63) == 0) redA[wave] = contrib;
    __syncthreads();
    if (tid == 0) {
        float total = 0.0f;
        #pragma unroll
        for (int w = 0; w < 16; ++w) total += redA[w];
        total *= (1.0f / (float)N);
        const bool masked_out = (sax == 0.0f) && (say == 0.0f);
        divs[p] = masked_out ? 0.0f : total;
    }
}

extern "C" __global__ void __launch_bounds__(256)
reduce_out_kernel(const float* __restrict__ divs, float* __restrict__ out)
{
    const int b   = blockIdx.x;
    const int tid = threadIdx.x;
    __shared__ float red[4];
    float v = divs[b * 256 + tid];        // 256 = S*NR problems per batch
    #pragma unroll
    for (int off = 32; off > 0; off >>= 1)
        v += __shfl_down(v, off, 64);
    if ((tid & 63) == 0) red[tid >> 6] = v;
    __syncthreads();
    if (tid == 0) out[b] = red[0] + red[1] + red[2] + red[3];
}

extern "C" void kernel_launch(void* const* d_in, const int* in_sizes, int n_in,
                              void* d_out, int out_size, void* d_ws, size_t ws_size,
                              hipStream_t stream) {
    const float* syn = (const float*)d_in[0];   // syn_data
    const float* obs = (const float*)d_in[1];   // obs_data
    float* divs = (float*)d_ws;                 // 512 floats scratch

    sinkhorn_div_kernel<<<NPROB, NT, 0, stream>>>(syn, obs, divs);
    reduce_out_kernel<<<2, 256, 0, stream>>>(divs, (float*)d_out);
}

// Round 15
// 555.940 us; speedup vs baseline: 1.0793x; 1.0793x over previous
//
#include <hip/hip_runtime.h>

// Sinkhorn divergence, 512 independent 256-point problems, 24 annealing steps.
// Round 17: R13 base (546us best: NT=512 pair-per-half full-row sweep,
// column-pair packed v2f math via pure-C __builtin_elementwise_fma,
// 1 barrier/step, dbuf H, VGPR cap 128) + 16-column online-update window:
// the per-window overhead (carry-fold + ceil + 2 ldexp + 2 cvt + 2 add,
// ~16 VALU) is paid 16x/step instead of 32x, and max trees are written in
// max3-fusable triples. Everything else byte-identical to R13.
// DO NOT use launch_bounds(1024,8) with v2f: hipcc pins VGPR=32 and demotes
// v2f to scratch (R3/R4/R14: WRITE_SIZE 150MB-5GB). (512,4) is the proven
// safe point (R13: VGPR 52, WRITE_SIZE 16).
// Ceiling arithmetic: 3.22e9 exp2 -> 786k trans-cyc/SIMD (328us) + ~330k
// VALU-cyc (138us) serialized ~ 471us floor; R13 = 546 (116%).
//
// Math: online logsumexp, integer-quantized running max (ceilf), ldexp
// rescale — exact; packed sum tree reassociates (threshold 5.48).

constexpr int   N       = 256;   // points per cloud
constexpr int   NPROB   = 512;   // B*S*NR
constexpr int   NRDIM   = 64;
constexpr float DT_F    = 0.001f;
constexpr float EPS_MIN = 1e-4f; // BLUR^P
constexpr int   NSTEPS  = 24;
constexpr float LOG2E   = 1.4426950408889634f;
constexpr float LN2     = 0.6931471805599453f;
constexpr int   NT      = 512;   // threads per block (8 waves)
constexpr int   NG      = N / 2; // 128 column-pair groups

typedef float v2f __attribute__((ext_vector_type(2)));

extern "C" __global__ void __launch_bounds__(NT, 4)
sinkhorn_div_kernel(const float* __restrict__ syn,
                    const float* __restrict__ obs,
                    float* __restrict__ divs)
{
    const int p    = blockIdx.x;         // ((b*S + s)*NR + r)
    const int r    = p & (NRDIM - 1);
    const int bs   = p >> 6;
    const int tid  = threadIdx.x;
    const int row  = tid & (N - 1);      // row index i
    const int pair = tid >> 8;           // 0: A={xy,yy} over y-side ; 1: B={yx,xx} over x-side

    __shared__ float4 yaH[2][NG];        // y-side H per buf (4 KB)
    __shared__ float4 xaH[2][NG];        // x-side H per buf (4 KB)
    __shared__ float4 yaW[NG];           // y-side coords (2 KB, static)
    __shared__ float4 xaW[NG];           // x-side coords (2 KB, static)
    __shared__ float  redA[32];

    float* yaHF = (float*)yaH;           // word views: buf*512 + wslot
    float* xaHF = (float*)xaH;
    float* yaWF = (float*)yaW;
    float* xaWF = (float*)xaW;

    const size_t base = (size_t)bs * N * NRDIM + r;
    const float xi = obs[base + (size_t)row * NRDIM];   // x cloud = obs
    const float yi = syn[base + (size_t)row * NRDIM];   // y cloud = syn
    const float ti = (float)row * DT_F;

    // word slot of column `row`: group g=row>>1, H1/z at g*4+(row&1), H2/t at +2
    const int wslot = ((row >> 1) << 2) | (row & 1);    // 0..509

    // ---- one-time init: static column coords ----
    if (pair == 0) {
        yaWF[wslot]     = yi;
        yaWF[wslot + 2] = ti;
    } else {
        xaWF[wslot]     = xi;
        xaWF[wslot + 2] = ti;
    }

    // ---- block reductions: diameter (max/min) + all-zero mask sums ----
    float hi = fmaxf(xi, yi), lo = fminf(xi, yi);
    float ax = fabsf(xi),     ay = fabsf(yi);
    #pragma unroll
    for (int off = 32; off > 0; off >>= 1) {
        hi  = fmaxf(hi, __shfl_down(hi, off, 64));
        lo  = fminf(lo, __shfl_down(lo, off, 64));
        ax += __shfl_down(ax, off, 64);
        ay += __shfl_down(ay, off, 64);
    }
    const int wave = tid >> 6;           // 0..7
    if ((tid & 63) == 0) {
        redA[wave * 4 + 0] = hi;  redA[wave * 4 + 1] = lo;
        redA[wave * 4 + 2] = ax;  redA[wave * 4 + 3] = ay;
    }
    __syncthreads();                     // also covers coord init writes
    float vmax = -3.4e38f, vmin = 3.4e38f, sax = 0.0f, say = 0.0f;
    #pragma unroll
    for (int w = 0; w < 8; ++w) {
        vmax = fmaxf(vmax, redA[w * 4 + 0]);
        vmin = fminf(vmin, redA[w * 4 + 1]);
        sax += redA[w * 4 + 2];
        say += redA[w * 4 + 3];
    }

    const float tspread  = 255.0f * DT_F;
    const float diameter = fmaxf(tspread, vmax - vmin);
    float eps_raw = diameter * diameter;              // eps0 = diameter^2

    const float selfx = 0.5f * (ti * ti + xi * xi);
    const float selfy = 0.5f * (ti * ti + yi * yi);
    const float la2   = -8.0f;                        // log2(1/256)

    // pair A: pot1=f (selfx, xi) reads y-side; pot2=py (selfy, yi)
    // pair B: pot1=g (selfy, yi) reads x-side; pot2=px (selfx, xi)
    const float self1 = (pair == 0) ? selfx : selfy;
    const float self2 = (pair == 0) ? selfy : selfx;
    const float cf1   = (pair == 0) ? xi : yi;
    const float cf2   = (pair == 0) ? yi : xi;

    float pot1 = 0.0f, pot2 = 0.0f;

#define EXP2(x) __builtin_amdgcn_exp2f(x)

// One 2-column group: Q = H quad, W = coord quad -> packed args AB (stream1),
// AC (stream2). Multiplicand pairs are loop-invariant; pure-C v2f fma.
#define GRP(I, AB, AC) do { \
        const float4 Q_ = Hq[k + (I)]; \
        const float4 W_ = Wq[k + (I)]; \
        const v2f hb_ = {Q_.x, Q_.y}; const v2f hc_ = {Q_.z, Q_.w}; \
        const v2f zz_ = {W_.x, W_.y}; const v2f tt_ = {W_.z, W_.w}; \
        AB = __builtin_elementwise_fma(zz_, c1v, \
                 __builtin_elementwise_fma(tt_, tii2, hb_)); \
        AC = __builtin_elementwise_fma(zz_, c2v, \
                 __builtin_elementwise_fma(tt_, tii2, hc_)); \
    } while (0)

    for (int step = 0; step < NSTEPS; ++step) {
        const float eps = fmaxf(eps_raw, EPS_MIN);
        const float inv = LOG2E / eps;
        const int   buf = step & 1;
        const int   bo  = buf * (NG * 4);        // word offset of H buffer

        // ---- prologue: cross-feed my potentials as next H columns ----
        const float h1 = fmaf(pot1 - self1, inv, la2);
        const float h2 = fmaf(pot2 - self2, inv, la2);
        if (pair == 0) {          // f -> Hyx (x-side H1) ; py -> Hyy (y-side H2)
            xaHF[bo + wslot]     = h1;
            yaHF[bo + wslot + 2] = h2;
        } else {                  // g -> Hxy (y-side H1) ; px -> Hxx (x-side H2)
            yaHF[bo + wslot]     = h1;
            xaHF[bo + wslot + 2] = h2;
        }
        __syncthreads();          // the ONLY barrier this step

        const float tii = ti * inv;
        const v2f tii2 = {tii, tii};
        const v2f c1v  = {cf1 * inv, cf1 * inv};
        const v2f c2v  = {cf2 * inv, cf2 * inv};
        const float4* __restrict__ Hq = (pair == 0) ? &yaH[buf][0] : &xaH[buf][0];
        const float4* __restrict__ Wq = (pair == 0) ? &yaW[0]      : &xaW[0];

        float m0 = -1e9f, m1 = -1e9f, s0 = 0.0f, s1 = 0.0f;
        #pragma unroll 2
        for (int k = 0; k < NG; k += 8) {        // 8 groups = 16 columns
            v2f ab0, ab1, ab2, ab3, ab4, ab5, ab6, ab7;
            v2f ac0, ac1, ac2, ac3, ac4, ac5, ac6, ac7;
            GRP(0, ab0, ac0);  GRP(1, ab1, ac1);
            GRP(2, ab2, ac2);  GRP(3, ab3, ac3);
            GRP(4, ab4, ac4);  GRP(5, ab5, ac5);
            GRP(6, ab6, ac6);  GRP(7, ab7, ac7);
            // max trees in max3-fusable triples; m0/m1 integer-valued
            // (or -1e9) -> folding before ceil stays exact
            const float b0t = fmaxf(fmaxf(ab0.x, ab0.y), ab1.x);
            const float b1t = fmaxf(fmaxf(ab1.y, ab2.x), ab2.y);
            const float b2t = fmaxf(fmaxf(ab3.x, ab3.y), ab4.x);
            const float b3t = fmaxf(fmaxf(ab4.y, ab5.x), ab5.y);
            const float b4t = fmaxf(fmaxf(ab6.x, ab6.y), ab7.x);
            const float b5t = fmaxf(ab7.y, m0);
            const float M0  = ceilf(fmaxf(fmaxf(fmaxf(b0t, b1t), b2t),
                                          fmaxf(fmaxf(b3t, b4t), b5t)));
            const float c0t = fmaxf(fmaxf(ac0.x, ac0.y), ac1.x);
            const float c1t = fmaxf(fmaxf(ac1.y, ac2.x), ac2.y);
            const float c2t = fmaxf(fmaxf(ac3.x, ac3.y), ac4.x);
            const float c3t = fmaxf(fmaxf(ac4.y, ac5.x), ac5.y);
            const float c4t = fmaxf(fmaxf(ac6.x, ac6.y), ac7.x);
            const float c5t = fmaxf(ac7.y, m1);
            const float M1  = ceilf(fmaxf(fmaxf(fmaxf(c0t, c1t), c2t),
                                          fmaxf(fmaxf(c3t, c4t), c5t)));
            const v2f M0v = {M0, M0};
            const v2f M1v = {M1, M1};
            const v2f ub0 = ab0 - M0v, ub1 = ab1 - M0v;
            const v2f ub2 = ab2 - M0v, ub3 = ab3 - M0v;
            const v2f ub4 = ab4 - M0v, ub5 = ab5 - M0v;
            const v2f ub6 = ab6 - M0v, ub7 = ab7 - M0v;
            const v2f uc0 = ac0 - M1v, uc1 = ac1 - M1v;
            const v2f uc2 = ac2 - M1v, uc3 = ac3 - M1v;
            const v2f uc4 = ac4 - M1v, uc5 = ac5 - M1v;
            const v2f uc6 = ac6 - M1v, uc7 = ac7 - M1v;
            v2f eb0, eb1, eb2, eb3, eb4, eb5, eb6, eb7;
            v2f ec0, ec1, ec2, ec3, ec4, ec5, ec6, ec7;
            eb0.x = EXP2(ub0.x); eb0.y = EXP2(ub0.y);
            eb1.x = EXP2(ub1.x); eb1.y = EXP2(ub1.y);
            eb2.x = EXP2(ub2.x); eb2.y = EXP2(ub2.y);
            eb3.x = EXP2(ub3.x); eb3.y = EXP2(ub3.y);
            eb4.x = EXP2(ub4.x); eb4.y = EXP2(ub4.y);
            eb5.x = EXP2(ub5.x); eb5.y = EXP2(ub5.y);
            eb6.x = EXP2(ub6.x); eb6.y = EXP2(ub6.y);
            eb7.x = EXP2(ub7.x); eb7.y = EXP2(ub7.y);
            ec0.x = EXP2(uc0.x); ec0.y = EXP2(uc0.y);
            ec1.x = EXP2(uc1.x); ec1.y = EXP2(uc1.y);
            ec2.x = EXP2(uc2.x); ec2.y = EXP2(uc2.y);
            ec3.x = EXP2(uc3.x); ec3.y = EXP2(uc3.y);
            ec4.x = EXP2(uc4.x); ec4.y = EXP2(uc4.y);
            ec5.x = EXP2(uc5.x); ec5.y = EXP2(uc5.y);
            ec6.x = EXP2(uc6.x); ec6.y = EXP2(uc6.y);
            ec7.x = EXP2(uc7.x); ec7.y = EXP2(uc7.y);
            const v2f pb0 = eb0 + eb1, pb1 = eb2 + eb3;
            const v2f pb2 = eb4 + eb5, pb3 = eb6 + eb7;
            const v2f qb  = (pb0 + pb1) + (pb2 + pb3);
            const v2f pc0 = ec0 + ec1, pc1 = ec2 + ec3;
            const v2f pc2 = ec4 + ec5, pc3 = ec6 + ec7;
            const v2f qc  = (pc0 + pc1) + (pc2 + pc3);
            s0 = ldexpf(s0, (int)(m0 - M0)) + (qb.x + qb.y);  m0 = M0;
            s1 = ldexpf(s1, (int)(m1 - M1)) + (qc.x + qc.y);  m1 = M1;
        }

        // ---- epilogue: thread-local softmin finish (2 logs) ----
        const float el2 = eps * LN2;
        pot1 = self1 - el2 * (m0 + __builtin_amdgcn_logf(s0));                  // f / g
        pot2 = 0.5f * (pot2 + (self2 - el2 * (m1 + __builtin_amdgcn_logf(s1)))); // py / px

        eps_raw *= 0.25f;
        // next prologue writes buf^1; step t's reads of buf are separated
        // from step t+2's writes of buf by step t+1's barrier.
    }
#undef GRP
#undef EXP2

    // ---- divergence: pair A holds (f - py), pair B holds (g - px) ----
    float contrib = pot1 - pot2;
    #pragma unroll
    for (int off = 32; off > 0; off >>= 1)
        contrib += __shfl_down(contrib, off, 64);
    __syncthreads();                      // redA reuse
    if ((tid & 63) == 0) redA[wave] = contrib;
    __syncthreads();
    if (tid == 0) {
        float total = 0.0f;
        #pragma unroll
        for (int w = 0; w < 8; ++w) total += redA[w];
        total *= (1.0f / (float)N);
        const bool masked_out = (sax == 0.0f) && (say == 0.0f);
        divs[p] = masked_out ? 0.0f : total;
    }
}

extern "C" __global__ void __launch_bounds__(256)
reduce_out_kernel(const float* __restrict__ divs, float* __restrict__ out)
{
    const int b   = blockIdx.x;
    const int tid = threadIdx.x;
    __shared__ float red[4];
    float v = divs[b * 256 + tid];        // 256 = S*NR problems per batch
    #pragma unroll
    for (int off = 32; off > 0; off >>= 1)
        v += __shfl_down(v, off, 64);
    if ((tid & 63) == 0) red[tid >> 6] = v;
    __syncthreads();
    if (tid == 0) out[b] = red[0] + red[1] + red[2] + red[3];
}

extern "C" void kernel_launch(void* const* d_in, const int* in_sizes, int n_in,
                              void* d_out, int out_size, void* d_ws, size_t ws_size,
                              hipStream_t stream) {
    const float* syn = (const float*)d_in[0];   // syn_data
    const float* obs = (const float*)d_in[1];   // obs_data
    float* divs = (float*)d_ws;                 // 512 floats scratch

    sinkhorn_div_kernel<<<NPROB, NT, 0, stream>>>(syn, obs, divs);
    reduce_out_kernel<<<2, 256, 0, stream>>>(divs, (float*)d_out);
}

// Round 16
// 542.807 us; speedup vs baseline: 1.1054x; 1.0242x over previous
//
#include <hip/hip_runtime.h>

// Sinkhorn divergence, 512 independent 256-point problems, 24 annealing steps.
// FINAL (R13 revert, session best 546.5us — 1.60x over the session-start
// 874us): R9 skeleton + column-pair packed v2f math.
//  - NT=512, pair-per-half: pair A={xy->f, yy->py} sweeps the y-side, pair
//    B={yx->g, xx->px} sweeps the x-side; each thread computes the FULL
//    256-column logsumexp for its two matrices per float4 read (0.5
//    b128/elem) -> complete softmins in-thread, no cross-thread combine.
//  - 1 barrier/step (double-buffered H arrays; potentials cross-feed
//    through a 2-word prologue write).
//  - Column-PAIR packed layout: every packed multiplicand is loop-invariant
//    ({tii,tii},{c1,c1},{c2,c2}) -> v_pk_fma_f32/v_pk_add_f32 selected from
//    pure-C v2f (__builtin_elementwise_fma). No inline asm, no op_sel.
//  - launch_bounds(512,4) = 128-VGPR cap is REQUIRED: (1024,8) pins VGPR=32
//    and demotes v2f to scratch (R3/R4/R14: 150MB-5GB spill traffic).
// Roofline: 3.22e9 exp2 -> 786k trans-cyc/SIMD (328us) + ~143us packed VALU,
// serialized issue floor ~471us; this kernel = 116% of floor. Nulls: load
// clustering (R7), occupancy 2x (R10/R14), wider online window (R15).
//
// Math (log2 domain): online logsumexp, integer-quantized running max
// (ceilf) with ldexp rescale — exact identity; packed sum tree reassociates
// (threshold 5.48, measured absmax 0).

constexpr int   N       = 256;   // points per cloud
constexpr int   NPROB   = 512;   // B*S*NR
constexpr int   NRDIM   = 64;
constexpr float DT_F    = 0.001f;
constexpr float EPS_MIN = 1e-4f; // BLUR^P
constexpr int   NSTEPS  = 24;
constexpr float LOG2E   = 1.4426950408889634f;
constexpr float LN2     = 0.6931471805599453f;
constexpr int   NT      = 512;   // threads per block (8 waves)
constexpr int   NG      = N / 2; // 128 column-pair groups

typedef float v2f __attribute__((ext_vector_type(2)));

extern "C" __global__ void __launch_bounds__(NT, 4)
sinkhorn_div_kernel(const float* __restrict__ syn,
                    const float* __restrict__ obs,
                    float* __restrict__ divs)
{
    const int p    = blockIdx.x;         // ((b*S + s)*NR + r)
    const int r    = p & (NRDIM - 1);
    const int bs   = p >> 6;
    const int tid  = threadIdx.x;
    const int row  = tid & (N - 1);      // row index i
    const int pair = tid >> 8;           // 0: A={xy,yy} over y-side ; 1: B={yx,xx} over x-side

    __shared__ float4 yaH[2][NG];        // y-side H per buf (4 KB)
    __shared__ float4 xaH[2][NG];        // x-side H per buf (4 KB)
    __shared__ float4 yaW[NG];           // y-side coords (2 KB, static)
    __shared__ float4 xaW[NG];           // x-side coords (2 KB, static)
    __shared__ float  redA[32];

    float* yaHF = (float*)yaH;           // word views: buf*512 + wslot
    float* xaHF = (float*)xaH;
    float* yaWF = (float*)yaW;
    float* xaWF = (float*)xaW;

    const size_t base = (size_t)bs * N * NRDIM + r;
    const float xi = obs[base + (size_t)row * NRDIM];   // x cloud = obs
    const float yi = syn[base + (size_t)row * NRDIM];   // y cloud = syn
    const float ti = (float)row * DT_F;

    // word slot of column `row`: group g=row>>1, H1/z at g*4+(row&1), H2/t at +2
    const int wslot = ((row >> 1) << 2) | (row & 1);    // 0..509

    // ---- one-time init: static column coords ----
    if (pair == 0) {
        yaWF[wslot]     = yi;
        yaWF[wslot + 2] = ti;
    } else {
        xaWF[wslot]     = xi;
        xaWF[wslot + 2] = ti;
    }

    // ---- block reductions: diameter (max/min) + all-zero mask sums ----
    float hi = fmaxf(xi, yi), lo = fminf(xi, yi);
    float ax = fabsf(xi),     ay = fabsf(yi);
    #pragma unroll
    for (int off = 32; off > 0; off >>= 1) {
        hi  = fmaxf(hi, __shfl_down(hi, off, 64));
        lo  = fminf(lo, __shfl_down(lo, off, 64));
        ax += __shfl_down(ax, off, 64);
        ay += __shfl_down(ay, off, 64);
    }
    const int wave = tid >> 6;           // 0..7
    if ((tid & 63) == 0) {
        redA[wave * 4 + 0] = hi;  redA[wave * 4 + 1] = lo;
        redA[wave * 4 + 2] = ax;  redA[wave * 4 + 3] = ay;
    }
    __syncthreads();                     // also covers coord init writes
    float vmax = -3.4e38f, vmin = 3.4e38f, sax = 0.0f, say = 0.0f;
    #pragma unroll
    for (int w = 0; w < 8; ++w) {
        vmax = fmaxf(vmax, redA[w * 4 + 0]);
        vmin = fminf(vmin, redA[w * 4 + 1]);
        sax += redA[w * 4 + 2];
        say += redA[w * 4 + 3];
    }

    const float tspread  = 255.0f * DT_F;
    const float diameter = fmaxf(tspread, vmax - vmin);
    float eps_raw = diameter * diameter;              // eps0 = diameter^2

    const float selfx = 0.5f * (ti * ti + xi * xi);
    const float selfy = 0.5f * (ti * ti + yi * yi);
    const float la2   = -8.0f;                        // log2(1/256)

    // pair A: pot1=f (selfx, xi) reads y-side; pot2=py (selfy, yi)
    // pair B: pot1=g (selfy, yi) reads x-side; pot2=px (selfx, xi)
    const float self1 = (pair == 0) ? selfx : selfy;
    const float self2 = (pair == 0) ? selfy : selfx;
    const float cf1   = (pair == 0) ? xi : yi;
    const float cf2   = (pair == 0) ? yi : xi;

    float pot1 = 0.0f, pot2 = 0.0f;

#define EXP2(x) __builtin_amdgcn_exp2f(x)

// One 2-column group: Q = H quad, W = coord quad -> packed args AB (stream1),
// AC (stream2). Multiplicand pairs are loop-invariant; pure-C v2f fma.
#define GRP(Q, W, AB, AC) do { \
        const v2f hb_ = {Q.x, Q.y}; const v2f hc_ = {Q.z, Q.w}; \
        const v2f zz_ = {W.x, W.y}; const v2f tt_ = {W.z, W.w}; \
        AB = __builtin_elementwise_fma(zz_, c1v, \
                 __builtin_elementwise_fma(tt_, tii2, hb_)); \
        AC = __builtin_elementwise_fma(zz_, c2v, \
                 __builtin_elementwise_fma(tt_, tii2, hc_)); \
    } while (0)

    for (int step = 0; step < NSTEPS; ++step) {
        const float eps = fmaxf(eps_raw, EPS_MIN);
        const float inv = LOG2E / eps;
        const int   buf = step & 1;
        const int   bo  = buf * (NG * 4);        // word offset of H buffer

        // ---- prologue: cross-feed my potentials as next H columns ----
        const float h1 = fmaf(pot1 - self1, inv, la2);
        const float h2 = fmaf(pot2 - self2, inv, la2);
        if (pair == 0) {          // f -> Hyx (x-side H1) ; py -> Hyy (y-side H2)
            xaHF[bo + wslot]     = h1;
            yaHF[bo + wslot + 2] = h2;
        } else {                  // g -> Hxy (y-side H1) ; px -> Hxx (x-side H2)
            yaHF[bo + wslot]     = h1;
            xaHF[bo + wslot + 2] = h2;
        }
        __syncthreads();          // the ONLY barrier this step

        const float tii = ti * inv;
        const v2f tii2 = {tii, tii};
        const v2f c1v  = {cf1 * inv, cf1 * inv};
        const v2f c2v  = {cf2 * inv, cf2 * inv};
        const float4* __restrict__ Hq = (pair == 0) ? &yaH[buf][0] : &xaH[buf][0];
        const float4* __restrict__ Wq = (pair == 0) ? &yaW[0]      : &xaW[0];

        float m0 = -1e9f, m1 = -1e9f, s0 = 0.0f, s1 = 0.0f;
        #pragma unroll 2
        for (int k = 0; k < NG; k += 4) {        // 4 groups = 8 columns
            const float4 Q0 = Hq[k + 0];
            const float4 Q1 = Hq[k + 1];
            const float4 Q2 = Hq[k + 2];
            const float4 Q3 = Hq[k + 3];
            const float4 W0 = Wq[k + 0];
            const float4 W1 = Wq[k + 1];
            const float4 W2 = Wq[k + 2];
            const float4 W3 = Wq[k + 3];
            v2f ab0, ab1, ab2, ab3, ac0, ac1, ac2, ac3;
            GRP(Q0, W0, ab0, ac0);
            GRP(Q1, W1, ab1, ac1);
            GRP(Q2, W2, ab2, ac2);
            GRP(Q3, W3, ab3, ac3);
            // scalar max trees on pair halves; m0/m1 integer-valued
            // (or -1e9) -> folding before ceil stays exact
            const float bt0 = fmaxf(fmaxf(ab0.x, ab0.y), ab1.x);
            const float bt1 = fmaxf(fmaxf(ab1.y, ab2.x), ab2.y);
            const float bt2 = fmaxf(fmaxf(ab3.x, ab3.y), m0);
            const float M0  = ceilf(fmaxf(fmaxf(bt0, bt1), bt2));
            const float ct0 = fmaxf(fmaxf(ac0.x, ac0.y), ac1.x);
            const float ct1 = fmaxf(fmaxf(ac1.y, ac2.x), ac2.y);
            const float ct2 = fmaxf(fmaxf(ac3.x, ac3.y), m1);
            const float M1  = ceilf(fmaxf(fmaxf(ct0, ct1), ct2));
            const v2f M0v = {M0, M0};
            const v2f M1v = {M1, M1};
            const v2f ub0 = ab0 - M0v, ub1 = ab1 - M0v;
            const v2f ub2 = ab2 - M0v, ub3 = ab3 - M0v;
            const v2f uc0 = ac0 - M1v, uc1 = ac1 - M1v;
            const v2f uc2 = ac2 - M1v, uc3 = ac3 - M1v;
            v2f eb0, eb1, eb2, eb3, ec0, ec1, ec2, ec3;
            eb0.x = EXP2(ub0.x); eb0.y = EXP2(ub0.y);
            eb1.x = EXP2(ub1.x); eb1.y = EXP2(ub1.y);
            eb2.x = EXP2(ub2.x); eb2.y = EXP2(ub2.y);
            eb3.x = EXP2(ub3.x); eb3.y = EXP2(ub3.y);
            ec0.x = EXP2(uc0.x); ec0.y = EXP2(uc0.y);
            ec1.x = EXP2(uc1.x); ec1.y = EXP2(uc1.y);
            ec2.x = EXP2(uc2.x); ec2.y = EXP2(uc2.y);
            ec3.x = EXP2(uc3.x); ec3.y = EXP2(uc3.y);
            const v2f pb0 = eb0 + eb1, pb1 = eb2 + eb3;
            const v2f qb  = pb0 + pb1;
            const v2f pc0 = ec0 + ec1, pc1 = ec2 + ec3;
            const v2f qc  = pc0 + pc1;
            s0 = ldexpf(s0, (int)(m0 - M0)) + (qb.x + qb.y);  m0 = M0;
            s1 = ldexpf(s1, (int)(m1 - M1)) + (qc.x + qc.y);  m1 = M1;
        }

        // ---- epilogue: thread-local softmin finish (2 logs) ----
        const float el2 = eps * LN2;
        pot1 = self1 - el2 * (m0 + __builtin_amdgcn_logf(s0));                  // f / g
        pot2 = 0.5f * (pot2 + (self2 - el2 * (m1 + __builtin_amdgcn_logf(s1)))); // py / px

        eps_raw *= 0.25f;
        // next prologue writes buf^1; step t's reads of buf are separated
        // from step t+2's writes of buf by step t+1's barrier.
    }
#undef GRP
#undef EXP2

    // ---- divergence: pair A holds (f - py), pair B holds (g - px) ----
    float contrib = pot1 - pot2;
    #pragma unroll
    for (int off = 32; off > 0; off >>= 1)
        contrib += __shfl_down(contrib, off, 64);
    __syncthreads();                      // redA reuse
    if ((tid & 63) == 0) redA[wave] = contrib;
    __syncthreads();
    if (tid == 0) {
        float total = 0.0f;
        #pragma unroll
        for (int w = 0; w < 8; ++w) total += redA[w];
        total *= (1.0f / (float)N);
        const bool masked_out = (sax == 0.0f) && (say == 0.0f);
        divs[p] = masked_out ? 0.0f : total;
    }
}

extern "C" __global__ void __launch_bounds__(256)
reduce_out_kernel(const float* __restrict__ divs, float* __restrict__ out)
{
    const int b   = blockIdx.x;
    const int tid = threadIdx.x;
    __shared__ float red[4];
    float v = divs[b * 256 + tid];        // 256 = S*NR problems per batch
    #pragma unroll
    for (int off = 32; off > 0; off >>= 1)
        v += __shfl_down(v, off, 64);
    if ((tid & 63) == 0) red[tid >> 6] = v;
    __syncthreads();
    if (tid == 0) out[b] = red[0] + red[1] + red[2] + red[3];
}

extern "C" void kernel_launch(void* const* d_in, const int* in_sizes, int n_in,
                              void* d_out, int out_size, void* d_ws, size_t ws_size,
                              hipStream_t stream) {
    const float* syn = (const float*)d_in[0];   // syn_data
    const float* obs = (const float*)d_in[1];   // obs_data
    float* divs = (float*)d_ws;                 // 512 floats scratch

    sinkhorn_div_kernel<<<NPROB, NT, 0, stream>>>(syn, obs, divs);
    reduce_out_kernel<<<2, 256, 0, stream>>>(divs, (float*)d_out);
}